// Round 1
// baseline (336.419 us; speedup 1.0000x reference)
//
#include <hip/hip_runtime.h>

#define HID 128
// LDS mean tile row stride in ushorts: 128 feats + 8 pad = 272 B/row.
// 272B stride => bank offset advances 4 banks/row => 2-way conflict (free, m136).
#define MEAN_STRIDE 136

typedef unsigned short ushort_t;
typedef unsigned int uint_t;
typedef float f32x4 __attribute__((ext_vector_type(4)));
typedef short s16x8 __attribute__((ext_vector_type(8)));

__device__ __forceinline__ ushort_t f2bf(float f) {
  uint_t u = __float_as_uint(f);
  uint_t r = (u + 0x7FFFu + ((u >> 16) & 1u)) >> 16;  // RNE
  return (ushort_t)r;
}
__device__ __forceinline__ float bfLo(uint_t v) { return __uint_as_float(v << 16); }
__device__ __forceinline__ float bfHi(uint_t v) { return __uint_as_float(v & 0xFFFF0000u); }

__device__ __forceinline__ uint4 pack8(const float4& lo, const float4& hi) {
  uint4 p;
  p.x = (uint_t)f2bf(lo.x) | ((uint_t)f2bf(lo.y) << 16);
  p.y = (uint_t)f2bf(lo.z) | ((uint_t)f2bf(lo.w) << 16);
  p.z = (uint_t)f2bf(hi.x) | ((uint_t)f2bf(hi.y) << 16);
  p.w = (uint_t)f2bf(hi.z) | ((uint_t)f2bf(hi.w) << 16);
  return p;
}

// ------- fused prep: 4-row gather + weight-swizzle + degree count -------
// R10: 2-deep gather was latency-bound (42.8us, VALUBusy 3.5%, 21% HBM).
// 4 rows/thread at quarter-N stride -> 4 indep x loads + 8 indep float4
// emb loads in flight per thread.
__global__ __launch_bounds__(256) void prep_kernel(
    const float* __restrict__ emb, const int* __restrict__ x,
    ushort_t* __restrict__ hb, int N,
    const float* __restrict__ Wl1, const float* __restrict__ Wr1,
    const float* __restrict__ Wl2, const float* __restrict__ Wr2,
    ushort_t* __restrict__ wsw,
    const int* __restrict__ dst, int* __restrict__ deg, int E) {
  int tid = blockIdx.x * 256 + threadIdx.x;
  const int qN = (N + 3) >> 2;
  int gthreads = qN * 16;
  if (tid < gthreads) {
    int r0 = tid >> 4, j = (tid & 15) * 8;
    int r1 = r0 + qN, r2 = r0 + 2 * qN, r3 = r0 + 3 * qN;
    int s0 = x[r0];
    int s1 = (r1 < N) ? x[r1] : s0;
    int s2 = (r2 < N) ? x[r2] : s0;
    int s3 = (r3 < N) ? x[r3] : s0;
    const float* p0 = &emb[(size_t)s0 * HID + j];
    const float* p1 = &emb[(size_t)s1 * HID + j];
    const float* p2 = &emb[(size_t)s2 * HID + j];
    const float* p3 = &emb[(size_t)s3 * HID + j];
    float4 a0 = *(const float4*)p0, a1 = *(const float4*)(p0 + 4);
    float4 b0 = *(const float4*)p1, b1 = *(const float4*)(p1 + 4);
    float4 c0 = *(const float4*)p2, c1 = *(const float4*)(p2 + 4);
    float4 d0 = *(const float4*)p3, d1 = *(const float4*)(p3 + 4);
    *(uint4*)&hb[(size_t)r0 * HID + j] = pack8(a0, a1);
    if (r1 < N) *(uint4*)&hb[(size_t)r1 * HID + j] = pack8(b0, b1);
    if (r2 < N) *(uint4*)&hb[(size_t)r2 * HID + j] = pack8(c0, c1);
    if (r3 < N) *(uint4*)&hb[(size_t)r3 * HID + j] = pack8(d0, d1);
    return;
  }
  tid -= gthreads;
  if (tid < 65536) {
    const float* srcs[4] = {Wl1, Wr1, Wl2, Wr2};
    int m = tid >> 14, idx = tid & 16383;
    int j = idx & 7;
    int lane = (idx >> 3) & 63;
    int nt = (idx >> 9) & 7;
    int ks = (idx >> 12) & 3;
    int row = nt * 16 + (lane & 15);
    int col = ks * 32 + (lane >> 4) * 8 + j;
    wsw[tid] = f2bf(srcs[m][row * HID + col]);
    return;
  }
  tid -= 65536;
  if (tid < E) atomicAdd(&deg[dst[tid]], 1);
}

// ---------------- CSR build ----------------
__global__ __launch_bounds__(256) void scan1_kernel(
    const int* __restrict__ deg, int* __restrict__ offsets,
    int* __restrict__ sums, int N) {
  __shared__ int s[256];
  int b = blockIdx.x, t = threadIdx.x;
  int base = b * 1024 + t * 4;
  int v0 = 0, v1 = 0, v2 = 0, v3 = 0;
  if (base + 0 < N) v0 = deg[base + 0];
  if (base + 1 < N) v1 = deg[base + 1];
  if (base + 2 < N) v2 = deg[base + 2];
  if (base + 3 < N) v3 = deg[base + 3];
  int mySum = v0 + v1 + v2 + v3;
  s[t] = mySum;
  __syncthreads();
  for (int off = 1; off < 256; off <<= 1) {
    int v = (t >= off) ? s[t - off] : 0;
    __syncthreads();
    s[t] += v;
    __syncthreads();
  }
  int excl = s[t] - mySum;
  if (t == 255) sums[b] = s[255];
  if (base + 0 < N) offsets[base + 0] = excl;
  if (base + 1 < N) offsets[base + 1] = excl + v0;
  if (base + 2 < N) offsets[base + 2] = excl + v0 + v1;
  if (base + 3 < N) offsets[base + 3] = excl + v0 + v1 + v2;
}

__global__ __launch_bounds__(256) void scan3_kernel(
    int* __restrict__ offsets, const int* __restrict__ sums,
    int* __restrict__ cursor, int N, int E, int nb) {
  __shared__ int red[256];
  int t = threadIdx.x;
  int chunk = (blockIdx.x * 256) >> 10;
  red[t] = (t < chunk) ? sums[t] : 0;
  __syncthreads();
  for (int off = 128; off > 0; off >>= 1) {
    if (t < off) red[t] += red[t + off];
    __syncthreads();
  }
  int prefix = red[0];
  int i = blockIdx.x * 256 + t;
  if (i < N) {
    int v = offsets[i] + prefix;
    offsets[i] = v;
    cursor[i] = v;
  } else if (i == N) {
    offsets[N] = E;
  }
}

__global__ __launch_bounds__(256) void fill_kernel(
    const int* __restrict__ src, const int* __restrict__ dst,
    int* __restrict__ cursor, int* __restrict__ csr, int E) {
  int e = blockIdx.x * 256 + threadIdx.x;
  if (e >= E) return;
  int d = dst[e];
  int pos = atomicAdd(&cursor[d], 1);
  csr[pos] = src[e];
}

// ---------------- fused layer: aggregate(mean) + MFMA GEMM ----------------
// R10 fusion: block owns 128 rows; quarter-wave aggregates 8 nodes' means
// into a padded LDS tile (no meanb global round-trip: -51MB/layer).
// Weights staged in 16KB quarters so LDS = 34816+16384 = 51200B -> 3 blk/CU.
// Output ping-pongs (hbIn != out buffer): no cross-block in-place race.
__global__ __launch_bounds__(256, 3) void fused_layer_kernel(
    const ushort_t* __restrict__ hbIn,
    const int* __restrict__ offsets, const int* __restrict__ csr,
    const ushort_t* __restrict__ WlS, const ushort_t* __restrict__ WrS,
    const float* __restrict__ bias,
    float* __restrict__ outF, ushort_t* __restrict__ outB,
    int N, int outIsBf16) {
  __shared__ ushort_t lmean[128 * MEAN_STRIDE];  // 34816 B
  __shared__ ushort_t ws[8192];                  // 16 KB weight stage
  const int t = threadIdx.x;
  const int lane = t & 63;
  const int wave = t >> 6;
  const int l15 = lane & 15;
  const int quad = lane >> 4;
  const int kq = quad * 8;
  const int blockRow = blockIdx.x * 128;
  const int waveRow = blockRow + wave * 32;
  const bool active = waveRow < N;

  // h A-frags (Wr half) for this wave's own rows — issue early, hidden
  // under the whole aggregate phase.
  int r0 = waveRow + l15;      if (r0 >= N) r0 = N - 1;
  int r1 = waveRow + 16 + l15; if (r1 >= N) r1 = N - 1;
  s16x8 ah0[4], ah1[4];
#pragma unroll
  for (int ks = 0; ks < 4; ks++) {
    ah0[ks] = *(const s16x8*)&hbIn[(size_t)r0 * HID + ks * 32 + kq];
    ah1[ks] = *(const s16x8*)&hbIn[(size_t)r1 * HID + ks * 32 + kq];
  }

  // ---- aggregate phase: quarter-wave qw owns local rows qw*8 .. qw*8+7 ----
  const int qw = t >> 4;
#pragma unroll 1
  for (int i = 0; i < 8; i++) {
    int rl = qw * 8 + i;
    int node = blockRow + rl;
    uint4 p;
    p.x = p.y = p.z = p.w = 0u;
    if (node < N) {
      int o0 = offsets[node], o1 = offsets[node + 1];
      float acc[8];
#pragma unroll
      for (int q = 0; q < 8; q++) acc[q] = 0.f;
      int e = o0;
      for (; e + 3 < o1; e += 4) {
        int s0 = csr[e], s1 = csr[e + 1], s2 = csr[e + 2], s3 = csr[e + 3];
        uint4 v0 = *(const uint4*)&hbIn[(size_t)s0 * HID + l15 * 8];
        uint4 v1 = *(const uint4*)&hbIn[(size_t)s1 * HID + l15 * 8];
        uint4 v2 = *(const uint4*)&hbIn[(size_t)s2 * HID + l15 * 8];
        uint4 v3 = *(const uint4*)&hbIn[(size_t)s3 * HID + l15 * 8];
        acc[0] += (bfLo(v0.x) + bfLo(v1.x)) + (bfLo(v2.x) + bfLo(v3.x));
        acc[1] += (bfHi(v0.x) + bfHi(v1.x)) + (bfHi(v2.x) + bfHi(v3.x));
        acc[2] += (bfLo(v0.y) + bfLo(v1.y)) + (bfLo(v2.y) + bfLo(v3.y));
        acc[3] += (bfHi(v0.y) + bfHi(v1.y)) + (bfHi(v2.y) + bfHi(v3.y));
        acc[4] += (bfLo(v0.z) + bfLo(v1.z)) + (bfLo(v2.z) + bfLo(v3.z));
        acc[5] += (bfHi(v0.z) + bfHi(v1.z)) + (bfHi(v2.z) + bfHi(v3.z));
        acc[6] += (bfLo(v0.w) + bfLo(v1.w)) + (bfLo(v2.w) + bfLo(v3.w));
        acc[7] += (bfHi(v0.w) + bfHi(v1.w)) + (bfHi(v2.w) + bfHi(v3.w));
      }
      if (e + 1 < o1) {
        int s0 = csr[e], s1 = csr[e + 1];
        uint4 v0 = *(const uint4*)&hbIn[(size_t)s0 * HID + l15 * 8];
        uint4 v1 = *(const uint4*)&hbIn[(size_t)s1 * HID + l15 * 8];
        acc[0] += bfLo(v0.x) + bfLo(v1.x);
        acc[1] += bfHi(v0.x) + bfHi(v1.x);
        acc[2] += bfLo(v0.y) + bfLo(v1.y);
        acc[3] += bfHi(v0.y) + bfHi(v1.y);
        acc[4] += bfLo(v0.z) + bfLo(v1.z);
        acc[5] += bfHi(v0.z) + bfHi(v1.z);
        acc[6] += bfLo(v0.w) + bfLo(v1.w);
        acc[7] += bfHi(v0.w) + bfHi(v1.w);
        e += 2;
      }
      if (e < o1) {
        int s0 = csr[e];
        uint4 v0 = *(const uint4*)&hbIn[(size_t)s0 * HID + l15 * 8];
        acc[0] += bfLo(v0.x); acc[1] += bfHi(v0.x);
        acc[2] += bfLo(v0.y); acc[3] += bfHi(v0.y);
        acc[4] += bfLo(v0.z); acc[5] += bfHi(v0.z);
        acc[6] += bfLo(v0.w); acc[7] += bfHi(v0.w);
      }
      int d = o1 - o0;
      float inv = 1.0f / (float)(d > 1 ? d : 1);
      p.x = (uint_t)f2bf(acc[0] * inv) | ((uint_t)f2bf(acc[1] * inv) << 16);
      p.y = (uint_t)f2bf(acc[2] * inv) | ((uint_t)f2bf(acc[3] * inv) << 16);
      p.z = (uint_t)f2bf(acc[4] * inv) | ((uint_t)f2bf(acc[5] * inv) << 16);
      p.w = (uint_t)f2bf(acc[6] * inv) | ((uint_t)f2bf(acc[7] * inv) << 16);
    }
    *(uint4*)&lmean[rl * MEAN_STRIDE + l15 * 8] = p;
  }
  __syncthreads();

  f32x4 acc[2][8];
#pragma unroll
  for (int mt = 0; mt < 2; mt++)
#pragma unroll
    for (int nt = 0; nt < 8; nt++) acc[mt][nt] = (f32x4){0.f, 0.f, 0.f, 0.f};

  // ---- half 0: mean @ Wl^T (A-frags from padded LDS tile) ----
#pragma unroll
  for (int kp = 0; kp < 2; kp++) {
#pragma unroll
    for (int it = 0; it < 4; it++) {
      int o = (it * 256 + t) * 8;
      *(s16x8*)&ws[o] = *(const s16x8*)&WlS[kp * 8192 + o];
    }
    __syncthreads();
    if (active) {
#pragma unroll
      for (int ks2 = 0; ks2 < 2; ks2++) {
        int ksg = kp * 2 + ks2;
        s16x8 a0 = *(const s16x8*)&lmean[(wave * 32 + l15) * MEAN_STRIDE + ksg * 32 + kq];
        s16x8 a1 = *(const s16x8*)&lmean[(wave * 32 + 16 + l15) * MEAN_STRIDE + ksg * 32 + kq];
#pragma unroll
        for (int nt = 0; nt < 8; nt++) {
          s16x8 b = *(const s16x8*)&ws[((ks2 * 8 + nt) * 64 + lane) * 8];
          acc[0][nt] = __builtin_amdgcn_mfma_f32_16x16x32_bf16(a0, b, acc[0][nt], 0, 0, 0);
          acc[1][nt] = __builtin_amdgcn_mfma_f32_16x16x32_bf16(a1, b, acc[1][nt], 0, 0, 0);
        }
      }
    }
    __syncthreads();
  }

  // ---- half 1: h @ Wr^T (A-frags from prefetched regs) ----
#pragma unroll
  for (int kp = 0; kp < 2; kp++) {
#pragma unroll
    for (int it = 0; it < 4; it++) {
      int o = (it * 256 + t) * 8;
      *(s16x8*)&ws[o] = *(const s16x8*)&WrS[kp * 8192 + o];
    }
    __syncthreads();
    if (active) {
#pragma unroll
      for (int ks2 = 0; ks2 < 2; ks2++) {
        int ksg = kp * 2 + ks2;
#pragma unroll
        for (int nt = 0; nt < 8; nt++) {
          s16x8 b = *(const s16x8*)&ws[((ks2 * 8 + nt) * 64 + lane) * 8];
          acc[0][nt] = __builtin_amdgcn_mfma_f32_16x16x32_bf16(ah0[ksg], b, acc[0][nt], 0, 0, 0);
          acc[1][nt] = __builtin_amdgcn_mfma_f32_16x16x32_bf16(ah1[ksg], b, acc[1][nt], 0, 0, 0);
        }
      }
    }
    __syncthreads();
  }

  if (active) {
#pragma unroll
    for (int mt = 0; mt < 2; mt++) {
#pragma unroll
      for (int nt = 0; nt < 8; nt++) {
        int col = nt * 16 + l15;
        float bv = bias[col];
#pragma unroll
        for (int r = 0; r < 4; r++) {
          int row = waveRow + mt * 16 + quad * 4 + r;
          if (row < N) {
            float v = fmaxf(acc[mt][nt][r] + bv, 0.f);
            if (outIsBf16) outB[(size_t)row * HID + col] = f2bf(v);
            else           outF[(size_t)row * HID + col] = v;
          }
        }
      }
    }
  }
}

extern "C" void kernel_launch(void* const* d_in, const int* in_sizes, int n_in,
                              void* d_out, int out_size, void* d_ws, size_t ws_size,
                              hipStream_t stream) {
  const int* x = (const int*)d_in[0];
  const int* ei = (const int*)d_in[1];
  const float* emb = (const float*)d_in[2];
  const float* Wl1 = (const float*)d_in[3];
  const float* bl1 = (const float*)d_in[4];
  const float* Wr1 = (const float*)d_in[5];
  const float* Wl2 = (const float*)d_in[6];
  const float* bl2 = (const float*)d_in[7];
  const float* Wr2 = (const float*)d_in[8];
  float* out = (float*)d_out;

  const int N = in_sizes[0];
  const int E = in_sizes[1] / 2;
  const int* srcI = ei;
  const int* dstI = ei + E;

  // workspace layout
  char* p = (char*)d_ws;
  ushort_t* hb = (ushort_t*)p;    p += (size_t)N * HID * sizeof(ushort_t);
  ushort_t* hb2 = (ushort_t*)p;   p += (size_t)N * HID * sizeof(ushort_t);
  ushort_t* wb = (ushort_t*)p;    p += (size_t)4 * 16384 * sizeof(ushort_t);
  int* deg = (int*)p;             p += (size_t)((N + 3) & ~3) * sizeof(int);
  int* offsets = (int*)p;         p += (size_t)((N + 4) & ~3) * sizeof(int);
  int* cursor = (int*)p;          p += (size_t)((N + 3) & ~3) * sizeof(int);
  int* csr = (int*)p;             p += (size_t)((E + 3) & ~3) * sizeof(int);
  int* sums = (int*)p;            p += 256 * sizeof(int);

  ushort_t* Wlb1 = wb;
  ushort_t* Wrb1 = wb + 16384;
  ushort_t* Wlb2 = wb + 32768;
  ushort_t* Wrb2 = wb + 49152;

  const int nScanBlocks = (N + 1023) / 1024;  // <=256 required
  const int eBlocks = (E + 255) / 256;
  const int gemmBlocks = (N + 127) / 128;
  const int qN = (N + 3) / 4;
  const int prepBlocks = (qN * 16 + 65536 + E + 255) / 256;

  // ---- CSR build + conversions ----
  hipMemsetAsync(deg, 0, (size_t)N * sizeof(int), stream);
  prep_kernel<<<prepBlocks, 256, 0, stream>>>(emb, x, hb, N,
                                              Wl1, Wr1, Wl2, Wr2, wb,
                                              dstI, deg, E);
  scan1_kernel<<<nScanBlocks, 256, 0, stream>>>(deg, offsets, sums, N);
  scan3_kernel<<<(N + 256) / 256, 256, 0, stream>>>(offsets, sums, cursor,
                                                    N, E, nScanBlocks);
  fill_kernel<<<eBlocks, 256, 0, stream>>>(srcI, dstI, cursor, csr, E);

  // ---- layer 1: hb -> hb2 (bf16), fused mean-agg + dual GEMM ----
  fused_layer_kernel<<<gemmBlocks, 256, 0, stream>>>(hb, offsets, csr,
                                                     Wlb1, Wrb1, bl1,
                                                     nullptr, hb2, N, 1);
  // ---- layer 2: hb2 -> out (f32) ----
  fused_layer_kernel<<<gemmBlocks, 256, 0, stream>>>(hb2, offsets, csr,
                                                     Wlb2, Wrb2, bl2,
                                                     out, nullptr, N, 0);
}

// Round 2
// 295.404 us; speedup vs baseline: 1.1388x; 1.1388x over previous
//
#include <hip/hip_runtime.h>

#define HID 128

typedef unsigned short ushort_t;
typedef unsigned int uint_t;
typedef float f32x4 __attribute__((ext_vector_type(4)));
typedef short s16x8 __attribute__((ext_vector_type(8)));

__device__ __forceinline__ ushort_t f2bf(float f) {
  uint_t u = __float_as_uint(f);
  uint_t r = (u + 0x7FFFu + ((u >> 16) & 1u)) >> 16;  // RNE
  return (ushort_t)r;
}
__device__ __forceinline__ float bfLo(uint_t v) { return __uint_as_float(v << 16); }
__device__ __forceinline__ float bfHi(uint_t v) { return __uint_as_float(v & 0xFFFF0000u); }

__device__ __forceinline__ uint4 pack8(const float4& lo, const float4& hi) {
  uint4 p;
  p.x = (uint_t)f2bf(lo.x) | ((uint_t)f2bf(lo.y) << 16);
  p.y = (uint_t)f2bf(lo.z) | ((uint_t)f2bf(lo.w) << 16);
  p.z = (uint_t)f2bf(hi.x) | ((uint_t)f2bf(hi.y) << 16);
  p.w = (uint_t)f2bf(hi.z) | ((uint_t)f2bf(hi.w) << 16);
  return p;
}

// ------- fused prep: 4-row gather + weight-swizzle + degree count -------
// R9: 1-deep gather latency-bound (43us, VALUBusy 3.7%). R10: 2-deep = 42.8us,
// still 21% HBM. R11: 4 rows/thread at quarter-N stride -> 4 indep x loads +
// 8 indep float4 emb loads in flight per thread.
__global__ __launch_bounds__(256) void prep_kernel(
    const float* __restrict__ emb, const int* __restrict__ x,
    ushort_t* __restrict__ hb, int N,
    const float* __restrict__ Wl1, const float* __restrict__ Wr1,
    const float* __restrict__ Wl2, const float* __restrict__ Wr2,
    ushort_t* __restrict__ wsw,
    const int* __restrict__ dst, int* __restrict__ deg, int E) {
  int tid = blockIdx.x * 256 + threadIdx.x;
  const int qN = (N + 3) >> 2;
  int gthreads = qN * 16;
  if (tid < gthreads) {
    int r0 = tid >> 4, j = (tid & 15) * 8;
    int r1 = r0 + qN, r2 = r0 + 2 * qN, r3 = r0 + 3 * qN;
    int s0 = x[r0];
    int s1 = (r1 < N) ? x[r1] : s0;
    int s2 = (r2 < N) ? x[r2] : s0;
    int s3 = (r3 < N) ? x[r3] : s0;
    const float* p0 = &emb[(size_t)s0 * HID + j];
    const float* p1 = &emb[(size_t)s1 * HID + j];
    const float* p2 = &emb[(size_t)s2 * HID + j];
    const float* p3 = &emb[(size_t)s3 * HID + j];
    float4 a0 = *(const float4*)p0, a1 = *(const float4*)(p0 + 4);
    float4 b0 = *(const float4*)p1, b1 = *(const float4*)(p1 + 4);
    float4 c0 = *(const float4*)p2, c1 = *(const float4*)(p2 + 4);
    float4 d0 = *(const float4*)p3, d1 = *(const float4*)(p3 + 4);
    *(uint4*)&hb[(size_t)r0 * HID + j] = pack8(a0, a1);
    if (r1 < N) *(uint4*)&hb[(size_t)r1 * HID + j] = pack8(b0, b1);
    if (r2 < N) *(uint4*)&hb[(size_t)r2 * HID + j] = pack8(c0, c1);
    if (r3 < N) *(uint4*)&hb[(size_t)r3 * HID + j] = pack8(d0, d1);
    return;
  }
  tid -= gthreads;
  if (tid < 65536) {
    const float* srcs[4] = {Wl1, Wr1, Wl2, Wr2};
    int m = tid >> 14, idx = tid & 16383;
    int j = idx & 7;
    int lane = (idx >> 3) & 63;
    int nt = (idx >> 9) & 7;
    int ks = (idx >> 12) & 3;
    int row = nt * 16 + (lane & 15);
    int col = ks * 32 + (lane >> 4) * 8 + j;
    wsw[tid] = f2bf(srcs[m][row * HID + col]);
    return;
  }
  tid -= 65536;
  if (tid < E) atomicAdd(&deg[dst[tid]], 1);
}

// ---------------- CSR build ----------------
__global__ __launch_bounds__(256) void scan1_kernel(
    const int* __restrict__ deg, int* __restrict__ offsets,
    int* __restrict__ sums, int N) {
  __shared__ int s[256];
  int b = blockIdx.x, t = threadIdx.x;
  int base = b * 1024 + t * 4;
  int v0 = 0, v1 = 0, v2 = 0, v3 = 0;
  if (base + 0 < N) v0 = deg[base + 0];
  if (base + 1 < N) v1 = deg[base + 1];
  if (base + 2 < N) v2 = deg[base + 2];
  if (base + 3 < N) v3 = deg[base + 3];
  int mySum = v0 + v1 + v2 + v3;
  s[t] = mySum;
  __syncthreads();
  for (int off = 1; off < 256; off <<= 1) {
    int v = (t >= off) ? s[t - off] : 0;
    __syncthreads();
    s[t] += v;
    __syncthreads();
  }
  int excl = s[t] - mySum;
  if (t == 255) sums[b] = s[255];
  if (base + 0 < N) offsets[base + 0] = excl;
  if (base + 1 < N) offsets[base + 1] = excl + v0;
  if (base + 2 < N) offsets[base + 2] = excl + v0 + v1;
  if (base + 3 < N) offsets[base + 3] = excl + v0 + v1 + v2;
}

__global__ __launch_bounds__(256) void scan3_kernel(
    int* __restrict__ offsets, const int* __restrict__ sums,
    int* __restrict__ cursor, int N, int E, int nb) {
  __shared__ int red[256];
  int t = threadIdx.x;
  int chunk = (blockIdx.x * 256) >> 10;
  red[t] = (t < chunk) ? sums[t] : 0;
  __syncthreads();
  for (int off = 128; off > 0; off >>= 1) {
    if (t < off) red[t] += red[t + off];
    __syncthreads();
  }
  int prefix = red[0];
  int i = blockIdx.x * 256 + t;
  if (i < N) {
    int v = offsets[i] + prefix;
    offsets[i] = v;
    cursor[i] = v;
  } else if (i == N) {
    offsets[N] = E;
  }
}

__global__ __launch_bounds__(256) void fill_kernel(
    const int* __restrict__ src, const int* __restrict__ dst,
    int* __restrict__ cursor, int* __restrict__ csr, int E) {
  int e = blockIdx.x * 256 + threadIdx.x;
  if (e >= E) return;
  int d = dst[e];
  int pos = atomicAdd(&cursor[d], 1);
  csr[pos] = src[e];
}

// ---------------- aggregate: one node per QUARTER-wave, 4-deep batch ----------------
// R11 lesson: this phase is gather-latency-bound and needs MAX occupancy
// (no LDS, small VGPR, 6250 blocks). Fusing it under the GEMM's grid shape
// (3 blk/CU, 12 waves) cost +20us/layer. Keep it standalone.
__global__ __launch_bounds__(256) void aggregate_kernel(
    const ushort_t* __restrict__ hb, const int* __restrict__ offsets,
    const int* __restrict__ csr, ushort_t* __restrict__ meanb, int N) {
  int t = threadIdx.x;
  int node = blockIdx.x * 16 + (t >> 4);
  if (node >= N) return;
  int l15 = t & 15;
  int o0 = offsets[node], o1 = offsets[node + 1];

  float acc[8];
#pragma unroll
  for (int i = 0; i < 8; i++) acc[i] = 0.f;

  int e = o0;
  for (; e + 3 < o1; e += 4) {
    int s0 = csr[e], s1 = csr[e + 1], s2 = csr[e + 2], s3 = csr[e + 3];
    uint4 v0 = *(const uint4*)&hb[(size_t)s0 * HID + l15 * 8];
    uint4 v1 = *(const uint4*)&hb[(size_t)s1 * HID + l15 * 8];
    uint4 v2 = *(const uint4*)&hb[(size_t)s2 * HID + l15 * 8];
    uint4 v3 = *(const uint4*)&hb[(size_t)s3 * HID + l15 * 8];
    acc[0] += (bfLo(v0.x) + bfLo(v1.x)) + (bfLo(v2.x) + bfLo(v3.x));
    acc[1] += (bfHi(v0.x) + bfHi(v1.x)) + (bfHi(v2.x) + bfHi(v3.x));
    acc[2] += (bfLo(v0.y) + bfLo(v1.y)) + (bfLo(v2.y) + bfLo(v3.y));
    acc[3] += (bfHi(v0.y) + bfHi(v1.y)) + (bfHi(v2.y) + bfHi(v3.y));
    acc[4] += (bfLo(v0.z) + bfLo(v1.z)) + (bfLo(v2.z) + bfLo(v3.z));
    acc[5] += (bfHi(v0.z) + bfHi(v1.z)) + (bfHi(v2.z) + bfHi(v3.z));
    acc[6] += (bfLo(v0.w) + bfLo(v1.w)) + (bfLo(v2.w) + bfLo(v3.w));
    acc[7] += (bfHi(v0.w) + bfHi(v1.w)) + (bfHi(v2.w) + bfHi(v3.w));
  }
  if (e + 1 < o1) {
    int s0 = csr[e], s1 = csr[e + 1];
    uint4 v0 = *(const uint4*)&hb[(size_t)s0 * HID + l15 * 8];
    uint4 v1 = *(const uint4*)&hb[(size_t)s1 * HID + l15 * 8];
    acc[0] += bfLo(v0.x) + bfLo(v1.x);
    acc[1] += bfHi(v0.x) + bfHi(v1.x);
    acc[2] += bfLo(v0.y) + bfLo(v1.y);
    acc[3] += bfHi(v0.y) + bfHi(v1.y);
    acc[4] += bfLo(v0.z) + bfLo(v1.z);
    acc[5] += bfHi(v0.z) + bfHi(v1.z);
    acc[6] += bfLo(v0.w) + bfLo(v1.w);
    acc[7] += bfHi(v0.w) + bfHi(v1.w);
    e += 2;
  }
  if (e < o1) {
    int s0 = csr[e];
    uint4 v0 = *(const uint4*)&hb[(size_t)s0 * HID + l15 * 8];
    acc[0] += bfLo(v0.x); acc[1] += bfHi(v0.x);
    acc[2] += bfLo(v0.y); acc[3] += bfHi(v0.y);
    acc[4] += bfLo(v0.z); acc[5] += bfHi(v0.z);
    acc[6] += bfLo(v0.w); acc[7] += bfHi(v0.w);
  }

  int d = o1 - o0;
  float inv = 1.0f / (float)(d > 1 ? d : 1);
  uint4 p;
  p.x = (uint_t)f2bf(acc[0] * inv) | ((uint_t)f2bf(acc[1] * inv) << 16);
  p.y = (uint_t)f2bf(acc[2] * inv) | ((uint_t)f2bf(acc[3] * inv) << 16);
  p.z = (uint_t)f2bf(acc[4] * inv) | ((uint_t)f2bf(acc[5] * inv) << 16);
  p.w = (uint_t)f2bf(acc[6] * inv) | ((uint_t)f2bf(acc[7] * inv) << 16);
  *(uint4*)&meanb[(size_t)node * HID + l15 * 8] = p;
}

// ---------------- MFMA GEMM: out = relu(mean@Wl^T + h@Wr^T + b) ----------------
// R12: weights staged in 32KB halves (Wl whole, then Wr whole) instead of one
// 64KB stage -> LDS 32768B, occupancy 2->3 blk/CU (VGPR-bound), better A-frag
// latency hiding. B-read indexing identical to the known-good R7 layout.
__global__ __launch_bounds__(256) void mfma_gemm_kernel(
    const ushort_t* __restrict__ meanb, const ushort_t* __restrict__ hb,
    const ushort_t* __restrict__ WlS, const ushort_t* __restrict__ WrS,
    const float* __restrict__ bias, float* __restrict__ outF,
    ushort_t* __restrict__ outB, int N, int outIsBf16) {
  __shared__ ushort_t ws[16384];  // 32 KB: one weight matrix at a time
  const int t = threadIdx.x;
  const int wave = t >> 6;
  const int lane = t & 63;
  const int rowBase = (blockIdx.x * 4 + wave) * 32;
  const int l15 = lane & 15;
  const int quad = lane >> 4;
  const int kq = quad * 8;
  const bool active = rowBase < N;

  int r0 = rowBase + l15;       if (r0 >= N) r0 = N - 1;
  int r1 = rowBase + 16 + l15;  if (r1 >= N) r1 = N - 1;

  // A-frag prefetch (independent of LDS staging)
  s16x8 a[2][2][4];  // [half][rowgrp][ks]
  if (active) {
#pragma unroll
    for (int ks = 0; ks < 4; ks++) {
      a[0][0][ks] = *(const s16x8*)&meanb[(size_t)r0 * HID + ks * 32 + kq];
      a[0][1][ks] = *(const s16x8*)&meanb[(size_t)r1 * HID + ks * 32 + kq];
      a[1][0][ks] = *(const s16x8*)&hb[(size_t)r0 * HID + ks * 32 + kq];
      a[1][1][ks] = *(const s16x8*)&hb[(size_t)r1 * HID + ks * 32 + kq];
    }
  }

  f32x4 acc[2][8];
#pragma unroll
  for (int mt = 0; mt < 2; mt++)
#pragma unroll
    for (int nt = 0; nt < 8; nt++) acc[mt][nt] = (f32x4){0.f, 0.f, 0.f, 0.f};

#pragma unroll
  for (int half = 0; half < 2; half++) {
    const ushort_t* W = half ? WrS : WlS;
    // stage one full weight matrix: contiguous 16B per thread, coalesced
#pragma unroll
    for (int it = 0; it < 8; it++) {
      int o = (it * 256 + t) * 8;
      *(s16x8*)&ws[o] = *(const s16x8*)&W[o];
    }
    __syncthreads();
    if (active) {
#pragma unroll
      for (int ks = 0; ks < 4; ks++)
#pragma unroll
        for (int nt = 0; nt < 8; nt++) {
          s16x8 b = *(const s16x8*)&ws[((ks * 8 + nt) * 64 + lane) * 8];
          acc[0][nt] = __builtin_amdgcn_mfma_f32_16x16x32_bf16(a[half][0][ks], b, acc[0][nt], 0, 0, 0);
          acc[1][nt] = __builtin_amdgcn_mfma_f32_16x16x32_bf16(a[half][1][ks], b, acc[1][nt], 0, 0, 0);
        }
    }
    if (half == 0) __syncthreads();  // protect ws before restaging
  }

  if (active) {
#pragma unroll
    for (int mt = 0; mt < 2; mt++) {
#pragma unroll
      for (int nt = 0; nt < 8; nt++) {
        int col = nt * 16 + l15;
        float bv = bias[col];
#pragma unroll
        for (int r = 0; r < 4; r++) {
          int row = rowBase + mt * 16 + quad * 4 + r;
          if (row < N) {
            float v = fmaxf(acc[mt][nt][r] + bv, 0.f);
            if (outIsBf16) outB[(size_t)row * HID + col] = f2bf(v);
            else           outF[(size_t)row * HID + col] = v;
          }
        }
      }
    }
  }
}

extern "C" void kernel_launch(void* const* d_in, const int* in_sizes, int n_in,
                              void* d_out, int out_size, void* d_ws, size_t ws_size,
                              hipStream_t stream) {
  const int* x = (const int*)d_in[0];
  const int* ei = (const int*)d_in[1];
  const float* emb = (const float*)d_in[2];
  const float* Wl1 = (const float*)d_in[3];
  const float* bl1 = (const float*)d_in[4];
  const float* Wr1 = (const float*)d_in[5];
  const float* Wl2 = (const float*)d_in[6];
  const float* bl2 = (const float*)d_in[7];
  const float* Wr2 = (const float*)d_in[8];
  float* out = (float*)d_out;

  const int N = in_sizes[0];
  const int E = in_sizes[1] / 2;
  const int* srcI = ei;
  const int* dstI = ei + E;

  // workspace layout
  char* p = (char*)d_ws;
  ushort_t* hb = (ushort_t*)p;    p += (size_t)N * HID * sizeof(ushort_t);
  ushort_t* hb2 = (ushort_t*)p;   p += (size_t)N * HID * sizeof(ushort_t);
  ushort_t* meanb = (ushort_t*)p; p += (size_t)N * HID * sizeof(ushort_t);
  ushort_t* wb = (ushort_t*)p;    p += (size_t)4 * 16384 * sizeof(ushort_t);
  int* deg = (int*)p;             p += (size_t)((N + 3) & ~3) * sizeof(int);
  int* offsets = (int*)p;         p += (size_t)((N + 4) & ~3) * sizeof(int);
  int* cursor = (int*)p;          p += (size_t)((N + 3) & ~3) * sizeof(int);
  int* csr = (int*)p;             p += (size_t)((E + 3) & ~3) * sizeof(int);
  int* sums = (int*)p;            p += 256 * sizeof(int);

  ushort_t* Wlb1 = wb;
  ushort_t* Wrb1 = wb + 16384;
  ushort_t* Wlb2 = wb + 32768;
  ushort_t* Wrb2 = wb + 49152;

  const int nScanBlocks = (N + 1023) / 1024;  // <=256 required
  const int eBlocks = (E + 255) / 256;
  const int gemmBlocks = (N + 127) / 128;
  const int aggBlocks = (N + 15) / 16;
  const int qN = (N + 3) / 4;
  const int prepBlocks = (qN * 16 + 65536 + E + 255) / 256;

  // ---- CSR build + conversions ----
  hipMemsetAsync(deg, 0, (size_t)N * sizeof(int), stream);
  prep_kernel<<<prepBlocks, 256, 0, stream>>>(emb, x, hb, N,
                                              Wl1, Wr1, Wl2, Wr2, wb,
                                              dstI, deg, E);
  scan1_kernel<<<nScanBlocks, 256, 0, stream>>>(deg, offsets, sums, N);
  scan3_kernel<<<(N + 256) / 256, 256, 0, stream>>>(offsets, sums, cursor,
                                                    N, E, nScanBlocks);
  fill_kernel<<<eBlocks, 256, 0, stream>>>(srcI, dstI, cursor, csr, E);

  // ---- layer 1: hb -> hb2 (bf16) ----
  aggregate_kernel<<<aggBlocks, 256, 0, stream>>>(hb, offsets, csr, meanb, N);
  mfma_gemm_kernel<<<gemmBlocks, 256, 0, stream>>>(meanb, hb, Wlb1, Wrb1, bl1,
                                                   nullptr, hb2, N, 1);

  // ---- layer 2: hb2 -> out (f32) ----
  aggregate_kernel<<<aggBlocks, 256, 0, stream>>>(hb2, offsets, csr, meanb, N);
  mfma_gemm_kernel<<<gemmBlocks, 256, 0, stream>>>(meanb, hb2, Wlb2, Wrb2, bl2,
                                                   out, nullptr, N, 0);
}

// Round 3
// 286.587 us; speedup vs baseline: 1.1739x; 1.0308x over previous
//
#include <hip/hip_runtime.h>

#define HID 128

typedef unsigned short ushort_t;
typedef unsigned int uint_t;
typedef float f32x4 __attribute__((ext_vector_type(4)));
typedef short s16x8 __attribute__((ext_vector_type(8)));

__device__ __forceinline__ ushort_t f2bf(float f) {
  uint_t u = __float_as_uint(f);
  uint_t r = (u + 0x7FFFu + ((u >> 16) & 1u)) >> 16;  // RNE
  return (ushort_t)r;
}
__device__ __forceinline__ float bfLo(uint_t v) { return __uint_as_float(v << 16); }
__device__ __forceinline__ float bfHi(uint_t v) { return __uint_as_float(v & 0xFFFF0000u); }

__device__ __forceinline__ uint4 pack8(const float4& lo, const float4& hi) {
  uint4 p;
  p.x = (uint_t)f2bf(lo.x) | ((uint_t)f2bf(lo.y) << 16);
  p.y = (uint_t)f2bf(lo.z) | ((uint_t)f2bf(lo.w) << 16);
  p.z = (uint_t)f2bf(hi.x) | ((uint_t)f2bf(hi.y) << 16);
  p.w = (uint_t)f2bf(hi.z) | ((uint_t)f2bf(hi.w) << 16);
  return p;
}

// ------- fused prep: 4-row gather + weight-swizzle + degree count -------
// R9: 1-deep gather latency-bound (43us, VALUBusy 3.7%). R10: 2-deep = 42.8us.
// R12: 4-deep -> fell out of top-5 (~30us). Keep.
__global__ __launch_bounds__(256) void prep_kernel(
    const float* __restrict__ emb, const int* __restrict__ x,
    ushort_t* __restrict__ hb, int N,
    const float* __restrict__ Wl1, const float* __restrict__ Wr1,
    const float* __restrict__ Wl2, const float* __restrict__ Wr2,
    ushort_t* __restrict__ wsw,
    const int* __restrict__ dst, int* __restrict__ deg, int E) {
  int tid = blockIdx.x * 256 + threadIdx.x;
  const int qN = (N + 3) >> 2;
  int gthreads = qN * 16;
  if (tid < gthreads) {
    int r0 = tid >> 4, j = (tid & 15) * 8;
    int r1 = r0 + qN, r2 = r0 + 2 * qN, r3 = r0 + 3 * qN;
    int s0 = x[r0];
    int s1 = (r1 < N) ? x[r1] : s0;
    int s2 = (r2 < N) ? x[r2] : s0;
    int s3 = (r3 < N) ? x[r3] : s0;
    const float* p0 = &emb[(size_t)s0 * HID + j];
    const float* p1 = &emb[(size_t)s1 * HID + j];
    const float* p2 = &emb[(size_t)s2 * HID + j];
    const float* p3 = &emb[(size_t)s3 * HID + j];
    float4 a0 = *(const float4*)p0, a1 = *(const float4*)(p0 + 4);
    float4 b0 = *(const float4*)p1, b1 = *(const float4*)(p1 + 4);
    float4 c0 = *(const float4*)p2, c1 = *(const float4*)(p2 + 4);
    float4 d0 = *(const float4*)p3, d1 = *(const float4*)(p3 + 4);
    *(uint4*)&hb[(size_t)r0 * HID + j] = pack8(a0, a1);
    if (r1 < N) *(uint4*)&hb[(size_t)r1 * HID + j] = pack8(b0, b1);
    if (r2 < N) *(uint4*)&hb[(size_t)r2 * HID + j] = pack8(c0, c1);
    if (r3 < N) *(uint4*)&hb[(size_t)r3 * HID + j] = pack8(d0, d1);
    return;
  }
  tid -= gthreads;
  if (tid < 65536) {
    const float* srcs[4] = {Wl1, Wr1, Wl2, Wr2};
    int m = tid >> 14, idx = tid & 16383;
    int j = idx & 7;
    int lane = (idx >> 3) & 63;
    int nt = (idx >> 9) & 7;
    int ks = (idx >> 12) & 3;
    int row = nt * 16 + (lane & 15);
    int col = ks * 32 + (lane >> 4) * 8 + j;
    wsw[tid] = f2bf(srcs[m][row * HID + col]);
    return;
  }
  tid -= 65536;
  if (tid < E) atomicAdd(&deg[dst[tid]], 1);
}

// ---------------- CSR build ----------------
__global__ __launch_bounds__(256) void scan1_kernel(
    const int* __restrict__ deg, int* __restrict__ offsets,
    int* __restrict__ sums, int N) {
  __shared__ int s[256];
  int b = blockIdx.x, t = threadIdx.x;
  int base = b * 1024 + t * 4;
  int v0 = 0, v1 = 0, v2 = 0, v3 = 0;
  if (base + 0 < N) v0 = deg[base + 0];
  if (base + 1 < N) v1 = deg[base + 1];
  if (base + 2 < N) v2 = deg[base + 2];
  if (base + 3 < N) v3 = deg[base + 3];
  int mySum = v0 + v1 + v2 + v3;
  s[t] = mySum;
  __syncthreads();
  for (int off = 1; off < 256; off <<= 1) {
    int v = (t >= off) ? s[t - off] : 0;
    __syncthreads();
    s[t] += v;
    __syncthreads();
  }
  int excl = s[t] - mySum;
  if (t == 255) sums[b] = s[255];
  if (base + 0 < N) offsets[base + 0] = excl;
  if (base + 1 < N) offsets[base + 1] = excl + v0;
  if (base + 2 < N) offsets[base + 2] = excl + v0 + v1;
  if (base + 3 < N) offsets[base + 3] = excl + v0 + v1 + v2;
}

__global__ __launch_bounds__(256) void scan3_kernel(
    int* __restrict__ offsets, const int* __restrict__ sums,
    int* __restrict__ cursor, int N, int E, int nb) {
  __shared__ int red[256];
  int t = threadIdx.x;
  int chunk = (blockIdx.x * 256) >> 10;
  red[t] = (t < chunk) ? sums[t] : 0;
  __syncthreads();
  for (int off = 128; off > 0; off >>= 1) {
    if (t < off) red[t] += red[t + off];
    __syncthreads();
  }
  int prefix = red[0];
  int i = blockIdx.x * 256 + t;
  if (i < N) {
    int v = offsets[i] + prefix;
    offsets[i] = v;
    cursor[i] = v;
  } else if (i == N) {
    offsets[N] = E;
  }
}

__global__ __launch_bounds__(256) void fill_kernel(
    const int* __restrict__ src, const int* __restrict__ dst,
    int* __restrict__ cursor, int* __restrict__ csr, int E) {
  int e = blockIdx.x * 256 + threadIdx.x;
  if (e >= E) return;
  int d = dst[e];
  int pos = atomicAdd(&cursor[d], 1);
  csr[pos] = src[e];
}

// ------- aggregate: one node per QUARTER-wave, masked 8-deep batch -------
// R11 lesson: gather-latency-bound, needs MAX occupancy -> standalone kernel.
// R13: mean degree 6 took TWO dependent csr->hb rounds with the 4/2/1 ladder.
// Masked 8-wide batch (clamped idx + validity fma) finishes deg<=8 nodes
// (~85% at Poisson(6)) in ONE round; duplicates hit the same cache line.
__global__ __launch_bounds__(256) void aggregate_kernel(
    const ushort_t* __restrict__ hb, const int* __restrict__ offsets,
    const int* __restrict__ csr, ushort_t* __restrict__ meanb, int N) {
  int t = threadIdx.x;
  int node = blockIdx.x * 16 + (t >> 4);
  if (node >= N) return;
  int l15 = t & 15;
  int o0 = offsets[node], o1 = offsets[node + 1];
  int last = o1 - 1;

  float acc[8];
#pragma unroll
  for (int i = 0; i < 8; i++) acc[i] = 0.f;

  for (int e = o0; e < o1; e += 8) {
    uint4 v[8];
    float m[8];
#pragma unroll
    for (int i = 0; i < 8; i++) {
      int idx = e + i;
      bool val = idx < o1;
      int s = csr[val ? idx : last];
      v[i] = *(const uint4*)&hb[(size_t)s * HID + l15 * 8];
      m[i] = val ? 1.f : 0.f;
    }
#pragma unroll
    for (int i = 0; i < 8; i++) {
      acc[0] = fmaf(m[i], bfLo(v[i].x), acc[0]);
      acc[1] = fmaf(m[i], bfHi(v[i].x), acc[1]);
      acc[2] = fmaf(m[i], bfLo(v[i].y), acc[2]);
      acc[3] = fmaf(m[i], bfHi(v[i].y), acc[3]);
      acc[4] = fmaf(m[i], bfLo(v[i].z), acc[4]);
      acc[5] = fmaf(m[i], bfHi(v[i].z), acc[5]);
      acc[6] = fmaf(m[i], bfLo(v[i].w), acc[6]);
      acc[7] = fmaf(m[i], bfHi(v[i].w), acc[7]);
    }
  }

  int d = o1 - o0;
  float inv = 1.0f / (float)(d > 1 ? d : 1);
  uint4 p;
  p.x = (uint_t)f2bf(acc[0] * inv) | ((uint_t)f2bf(acc[1] * inv) << 16);
  p.y = (uint_t)f2bf(acc[2] * inv) | ((uint_t)f2bf(acc[3] * inv) << 16);
  p.z = (uint_t)f2bf(acc[4] * inv) | ((uint_t)f2bf(acc[5] * inv) << 16);
  p.w = (uint_t)f2bf(acc[6] * inv) | ((uint_t)f2bf(acc[7] * inv) << 16);
  *(uint4*)&meanb[(size_t)node * HID + l15 * 8] = p;
}

// ---------------- MFMA GEMM (R7/R0 known-good): out = relu(mean@Wl^T + h@Wr^T + b) ----------------
// R13: REVERTED to single 64KB stage. R12's 32KB half-staging added an exposed
// L2 round-trip mid-kernel (gemm 40->51us; half0's 64 MFMAs can't hide the Wr
// stage). Both matrices' staging loads must be in flight together, one sync.
__global__ __launch_bounds__(256) void mfma_gemm_kernel(
    const ushort_t* __restrict__ meanb, const ushort_t* __restrict__ hb,
    const ushort_t* __restrict__ WlS, const ushort_t* __restrict__ WrS,
    const float* __restrict__ bias, float* __restrict__ outF,
    ushort_t* __restrict__ outB, int N, int outIsBf16) {
  __shared__ ushort_t ws[32768];  // 64 KB: [0..16383]=Wl frags, rest = Wr
  const int t = threadIdx.x;
  const int wave = t >> 6;
  const int lane = t & 63;
  const int rowBase = (blockIdx.x * 4 + wave) * 32;
  const int l15 = lane & 15;
  const int quad = lane >> 4;
  const int kq = quad * 8;
  const bool active = rowBase < N;

  int r0 = rowBase + l15;       if (r0 >= N) r0 = N - 1;
  int r1 = rowBase + 16 + l15;  if (r1 >= N) r1 = N - 1;

  // A-frag prefetch (independent of LDS staging)
  s16x8 a[2][2][4];  // [half][rowgrp][ks]
  if (active) {
#pragma unroll
    for (int ks = 0; ks < 4; ks++) {
      a[0][0][ks] = *(const s16x8*)&meanb[(size_t)r0 * HID + ks * 32 + kq];
      a[0][1][ks] = *(const s16x8*)&meanb[(size_t)r1 * HID + ks * 32 + kq];
      a[1][0][ks] = *(const s16x8*)&hb[(size_t)r0 * HID + ks * 32 + kq];
      a[1][1][ks] = *(const s16x8*)&hb[(size_t)r1 * HID + ks * 32 + kq];
    }
  }

  // stage both weight matrices: contiguous 16B per thread, coalesced
#pragma unroll
  for (int it = 0; it < 8; it++) {
    int o = (it * 256 + t) * 8;
    *(s16x8*)&ws[o] = *(const s16x8*)&WlS[o];
    *(s16x8*)&ws[16384 + o] = *(const s16x8*)&WrS[o];
  }
  __syncthreads();

  if (active) {
    f32x4 acc[2][8];
#pragma unroll
    for (int mt = 0; mt < 2; mt++)
#pragma unroll
      for (int nt = 0; nt < 8; nt++) acc[mt][nt] = (f32x4){0.f, 0.f, 0.f, 0.f};

#pragma unroll
    for (int half = 0; half < 2; half++) {
      const int hbase = half * 16384;
#pragma unroll
      for (int ks = 0; ks < 4; ks++)
#pragma unroll
        for (int nt = 0; nt < 8; nt++) {
          s16x8 b = *(const s16x8*)&ws[hbase + ((ks * 8 + nt) * 64 + lane) * 8];
          acc[0][nt] = __builtin_amdgcn_mfma_f32_16x16x32_bf16(a[half][0][ks], b, acc[0][nt], 0, 0, 0);
          acc[1][nt] = __builtin_amdgcn_mfma_f32_16x16x32_bf16(a[half][1][ks], b, acc[1][nt], 0, 0, 0);
        }
    }

#pragma unroll
    for (int mt = 0; mt < 2; mt++) {
#pragma unroll
      for (int nt = 0; nt < 8; nt++) {
        int col = nt * 16 + l15;
        float bv = bias[col];
#pragma unroll
        for (int r = 0; r < 4; r++) {
          int row = rowBase + mt * 16 + quad * 4 + r;
          if (row < N) {
            float v = fmaxf(acc[mt][nt][r] + bv, 0.f);
            if (outIsBf16) outB[(size_t)row * HID + col] = f2bf(v);
            else           outF[(size_t)row * HID + col] = v;
          }
        }
      }
    }
  }
}

extern "C" void kernel_launch(void* const* d_in, const int* in_sizes, int n_in,
                              void* d_out, int out_size, void* d_ws, size_t ws_size,
                              hipStream_t stream) {
  const int* x = (const int*)d_in[0];
  const int* ei = (const int*)d_in[1];
  const float* emb = (const float*)d_in[2];
  const float* Wl1 = (const float*)d_in[3];
  const float* bl1 = (const float*)d_in[4];
  const float* Wr1 = (const float*)d_in[5];
  const float* Wl2 = (const float*)d_in[6];
  const float* bl2 = (const float*)d_in[7];
  const float* Wr2 = (const float*)d_in[8];
  float* out = (float*)d_out;

  const int N = in_sizes[0];
  const int E = in_sizes[1] / 2;
  const int* srcI = ei;
  const int* dstI = ei + E;

  // workspace layout
  char* p = (char*)d_ws;
  ushort_t* hb = (ushort_t*)p;    p += (size_t)N * HID * sizeof(ushort_t);
  ushort_t* hb2 = (ushort_t*)p;   p += (size_t)N * HID * sizeof(ushort_t);
  ushort_t* meanb = (ushort_t*)p; p += (size_t)N * HID * sizeof(ushort_t);
  ushort_t* wb = (ushort_t*)p;    p += (size_t)4 * 16384 * sizeof(ushort_t);
  int* deg = (int*)p;             p += (size_t)((N + 3) & ~3) * sizeof(int);
  int* offsets = (int*)p;         p += (size_t)((N + 4) & ~3) * sizeof(int);
  int* cursor = (int*)p;          p += (size_t)((N + 3) & ~3) * sizeof(int);
  int* csr = (int*)p;             p += (size_t)((E + 3) & ~3) * sizeof(int);
  int* sums = (int*)p;            p += 256 * sizeof(int);

  ushort_t* Wlb1 = wb;
  ushort_t* Wrb1 = wb + 16384;
  ushort_t* Wlb2 = wb + 32768;
  ushort_t* Wrb2 = wb + 49152;

  const int nScanBlocks = (N + 1023) / 1024;  // <=256 required
  const int eBlocks = (E + 255) / 256;
  const int gemmBlocks = (N + 127) / 128;
  const int aggBlocks = (N + 15) / 16;
  const int qN = (N + 3) / 4;
  const int prepBlocks = (qN * 16 + 65536 + E + 255) / 256;

  // ---- CSR build + conversions ----
  hipMemsetAsync(deg, 0, (size_t)N * sizeof(int), stream);
  prep_kernel<<<prepBlocks, 256, 0, stream>>>(emb, x, hb, N,
                                              Wl1, Wr1, Wl2, Wr2, wb,
                                              dstI, deg, E);
  scan1_kernel<<<nScanBlocks, 256, 0, stream>>>(deg, offsets, sums, N);
  scan3_kernel<<<(N + 256) / 256, 256, 0, stream>>>(offsets, sums, cursor,
                                                    N, E, nScanBlocks);
  fill_kernel<<<eBlocks, 256, 0, stream>>>(srcI, dstI, cursor, csr, E);

  // ---- layer 1: hb -> hb2 (bf16) ----
  aggregate_kernel<<<aggBlocks, 256, 0, stream>>>(hb, offsets, csr, meanb, N);
  mfma_gemm_kernel<<<gemmBlocks, 256, 0, stream>>>(meanb, hb, Wlb1, Wrb1, bl1,
                                                   nullptr, hb2, N, 1);

  // ---- layer 2: hb2 -> out (f32) ----
  aggregate_kernel<<<aggBlocks, 256, 0, stream>>>(hb2, offsets, csr, meanb, N);
  mfma_gemm_kernel<<<gemmBlocks, 256, 0, stream>>>(meanb, hb2, Wlb2, Wrb2, bl2,
                                                   out, nullptr, N, 0);
}